// Round 9
// baseline (609.782 us; speedup 1.0000x reference)
//
#include <hip/hip_runtime.h>
#include <math.h>

typedef __attribute__((ext_vector_type(8))) _Float16 half8v;   // 8 fp16 = 4 VGPR
typedef __attribute__((ext_vector_type(4))) _Float16 half4v;
typedef __attribute__((ext_vector_type(4))) float f32x4;

__device__ __forceinline__ void gload16(const void* g, void* l) {
  // global -> LDS direct DMA, 16 B per lane. LDS dest = wave-uniform base + lane*16.
  __builtin_amdgcn_global_load_lds(
      (const __attribute__((address_space(1))) void*)g,
      (__attribute__((address_space(3))) void*)l, 16, 0, 0);
}

// ============ weight prep: W[k][n] fp32 -> Wt[n][k] fp16 (transpose+cast) ============
struct WP { const float* src; _Float16* dst; };
struct WPArgs { WP w[6]; };

__global__ __launch_bounds__(256)
void wprep_kernel(WPArgs args) {
  __shared__ float tile[32][33];
  const WP wp = args.w[blockIdx.z];
  const int t  = threadIdx.x;
  const int r  = t >> 3;            // 0..31
  const int c  = (t & 7) * 4;       // 0..28
  const int n0 = blockIdx.x * 32;
  const int k0 = blockIdx.y * 32;
  float4 v = *(const float4*)(wp.src + (size_t)(k0 + r) * 1024 + n0 + c);
  tile[r][c] = v.x; tile[r][c + 1] = v.y; tile[r][c + 2] = v.z; tile[r][c + 3] = v.w;
  __syncthreads();
  half4v h;
  #pragma unroll
  for (int i = 0; i < 4; ++i) h[i] = (_Float16)tile[c + i][r];
  *(half4v*)(wp.dst + (size_t)(n0 + r) * 1024 + k0 + c) = h;
}

// ============ cast: fp32 -> fp16 (same layout) ============
__global__ __launch_bounds__(256)
void aconv_kernel(const float* __restrict__ in, _Float16* __restrict__ out, int n4) {
  int i = blockIdx.x * 256 + threadIdx.x;
  if (i >= n4) return;
  float4 v = ((const float4*)in)[i];
  half4v o;
  o[0] = (_Float16)v.x; o[1] = (_Float16)v.y; o[2] = (_Float16)v.z; o[3] = (_Float16)v.w;
  ((half4v*)out)[i] = o;
}

// ============ composed bias: out[n] = sum_k bk[k]*Wvt[n][k] + bv[n] ============
__global__ __launch_bounds__(256)
void bias_compose(const float* __restrict__ bk, const float* __restrict__ bv,
                  const _Float16* __restrict__ Wvt, float* __restrict__ out) {
  const int n = blockIdx.x * 256 + threadIdx.x;   // 0..1023
  const _Float16* row = Wvt + (size_t)n * 1024;
  float s = bv[n];
  for (int k = 0; k < 1024; k += 8) {
    half8v wv = *(const half8v*)&row[k];
    #pragma unroll
    for (int j = 0; j < 8; ++j) s += bk[k + j] * (float)wv[j];
  }
  out[n] = s;
}

// ============ fp16 MFMA GEMM: C[M, NN*128] = A @ B^T + bias ============
// 1D grid (NM*NN blocks), XCD-chunked: xcd=bid&7 owns contiguous m-rows, n fastest.
// 128x128 tile, BK=64, 4 waves, global_load_lds staging.
// MODE 0: C fp16 row-major [M][1024].
// MODE 1: Cf = X + relu(C+bias) fp32 (direct stores).
// MODE 2: C TRANSPOSED fp16 -> Vt[n*ostride + m].
// MODE 3: n<1024 -> C fp16 (as MODE 0); n>=1024 -> Vt[(n-1024)*ostride + m].
template<int MODE>
__global__ __launch_bounds__(256)
void gemm_fp16(const _Float16* __restrict__ A, const _Float16* __restrict__ B,
               const float* __restrict__ bias, const _Float16* __restrict__ X,
               _Float16* __restrict__ C, float* __restrict__ Cf,
               _Float16* __restrict__ Vt, int NM, int NN, int ostride) {
  __shared__ _Float16 smem[16384];            // 32KB: sA | sB ; reused as sT epilogue
  _Float16* const sA = smem;
  _Float16* const sB = smem + 8192;
  const int t    = threadIdx.x;
  const int bid  = blockIdx.x;
  const int xcd  = bid & 7;
  const int li   = bid >> 3;
  const int m    = xcd * (NM >> 3) + li / NN;
  const int n    = li % NN;
  const int bm   = m * 128;
  const int bn   = n * 128;
  const int lane = t & 63;
  const int w    = t >> 6;
  const int wr   = (w >> 1) * 64;
  const int wc   = (w & 1) * 64;
  const int lm   = lane & 15;
  const int lq   = lane >> 4;

  f32x4 acc[4][4];
  #pragma unroll
  for (int i = 0; i < 4; ++i)
    #pragma unroll
    for (int j = 0; j < 4; ++j) { f32x4 z = {0.f, 0.f, 0.f, 0.f}; acc[i][j] = z; }

  for (int k0 = 0; k0 < 1024; k0 += 64) {
    __syncthreads();                     // frag reads of previous iter complete
    #pragma unroll
    for (int i = 0; i < 4; ++i) {
      const int T    = w * 4 + i;        // 0..15: kq = T>>1, row-half = T&1
      const int kq   = T >> 1;
      const int row  = (T & 1) * 64 + lane;
      gload16(A + (size_t)(bm + row) * 1024 + k0 + kq * 8, &sA[(T * 64 + lane) * 8]);
      gload16(B + (size_t)(bn + row) * 1024 + k0 + kq * 8, &sB[(T * 64 + lane) * 8]);
    }
    __syncthreads();                     // vmcnt drained before barrier

    #pragma unroll
    for (int kk = 0; kk < 2; ++kk) {
      half8v af[4], bf[4];
      #pragma unroll
      for (int mi = 0; mi < 4; ++mi)
        af[mi] = *(const half8v*)&sA[((kk * 4 + lq) * 128 + wr + mi * 16 + lm) * 8];
      #pragma unroll
      for (int ni = 0; ni < 4; ++ni)
        bf[ni] = *(const half8v*)&sB[((kk * 4 + lq) * 128 + wc + ni * 16 + lm) * 8];
      #pragma unroll
      for (int mi = 0; mi < 4; ++mi)
        #pragma unroll
        for (int ni = 0; ni < 4; ++ni)
          acc[mi][ni] = __builtin_amdgcn_mfma_f32_16x16x32_f16(af[mi], bf[ni], acc[mi][ni], 0, 0, 0);
    }
  }

  float bv[4];
  #pragma unroll
  for (int ni = 0; ni < 4; ++ni) bv[ni] = bias[bn + wc + ni * 16 + lm];

  if (MODE == 1) {
    #pragma unroll
    for (int mi = 0; mi < 4; ++mi)
      #pragma unroll
      for (int ni = 0; ni < 4; ++ni) {
        const int col = bn + wc + ni * 16 + lm;
        #pragma unroll
        for (int j = 0; j < 4; ++j) {
          const int row = bm + wr + mi * 16 + lq * 4 + j;
          const size_t idx = (size_t)row * 1024 + col;
          Cf[idx] = (float)X[idx] + fmaxf(acc[mi][ni][j] + bv[ni], 0.f);
        }
      }
    return;
  }

  // MODE 0 / 2 / 3: stage tile in LDS, then coalesced 16B-per-lane writes.
  const bool tr = (MODE == 2) || (MODE == 3 && bn >= 1024);   // block-uniform
  __syncthreads();                       // all waves done reading sA/sB
  #pragma unroll
  for (int mi = 0; mi < 4; ++mi)
    #pragma unroll
    for (int ni = 0; ni < 4; ++ni) {
      const int cc = wc + ni * 16 + lm;
      #pragma unroll
      for (int j = 0; j < 4; ++j) {
        const int rr = wr + mi * 16 + lq * 4 + j;
        const _Float16 v = (_Float16)(acc[mi][ni][j] + bv[ni]);
        if (!tr) smem[rr * 128 + cc] = v;    // sT[m][n]
        else     smem[cc * 128 + rr] = v;    // sT[n][m] (transposed out)
      }
    }
  __syncthreads();
  const int r16 = t >> 4;                // 0..15
  const int c8  = (t & 15) * 8;          // 0..120
  #pragma unroll
  for (int p = 0; p < 8; ++p) {
    const int row = p * 16 + r16;
    half8v vv = *(const half8v*)&smem[row * 128 + c8];
    if (!tr) {
      *(half8v*)(C + (size_t)(bm + row) * 1024 + bn + c8) = vv;
    } else {
      const int nb = (MODE == 3) ? (bn - 1024) : bn;
      *(half8v*)(Vt + (size_t)(nb + row) * ostride + bm + c8) = vv;
    }
  }
}

// ============ MFMA attention (fp16) ============
// Grid (hb=128, ks=2). 1024 threads = 16 waves; wave w owns q in [w*32, w*32+32).
// 32 k-tiles of 32. Softmax over q => Z[k] block-local. Per tile: reg-prefetched
// double-buffered K/V staging (2 barriers), S = fp16 MFMA, Z via shfl +
// cross-wave LDS, P*invZ fp16 to per-wave LDS (no barrier), PV MFMA.
__global__ __launch_bounds__(1024, 4)
void attn_mfma(const _Float16* __restrict__ Qp,
               const _Float16* __restrict__ K1p, const _Float16* __restrict__ K2p,
               const _Float16* __restrict__ VT1, const _Float16* __restrict__ VT2,
               float* __restrict__ Opart) {
  __shared__ _Float16 sK[2][2048];     // [buf][dchunk 8][k 32][8]   8KB
  __shared__ _Float16 sV[2][2560];     // [buf][d 64][k 32 pad->40] 10KB
  __shared__ _Float16 sP[20480];       // per-wave [q 32][k 32 pad->40] 40KB
  __shared__ float sZ[16][32];         // per-wave column partials   2KB

  const int t    = threadIdx.x;
  const int lane = t & 63;
  const int w    = t >> 6;             // wave 0..15
  const int lm   = lane & 15;
  const int lq   = lane >> 4;
  const int hb   = blockIdx.x;
  const int ks   = blockIdx.y;
  const int h    = hb >> 3;
  const int b    = hb & 7;
  const int qw   = w * 32;
  const _Float16* __restrict__ K  = ks ? K2p : K1p;
  const _Float16* __restrict__ VT = ks ? VT2 : VT1;

  half8v qf[2][2];
  #pragma unroll
  for (int mi = 0; mi < 2; ++mi)
    #pragma unroll
    for (int dh = 0; dh < 2; ++dh)
      qf[mi][dh] = *(const half8v*)(Qp + (size_t)(b * 512 + qw + mi * 16 + lm) * 1024
                                       + h * 64 + dh * 32 + lq * 8);

  f32x4 o[2][4];
  #pragma unroll
  for (int i = 0; i < 2; ++i)
    #pragma unroll
    for (int j = 0; j < 4; ++j) { f32x4 z = {0.f, 0.f, 0.f, 0.f}; o[i][j] = z; }

  const int ku = t & 255;
  const int sd = ku & 31;              // K: k row
  const int sc = ku >> 5;              // K: d chunk 0..7
  const int vd = ku & 63;              // V: d row
  const int vc = (ku >> 6) & 3;        // V: k chunk 0..3
  _Float16* sPw = sP + w * 1280;       // per-wave 32x40

  half8v rk, rv;
  #define ISSUE_LOADS(K0)                                                                  \
    if (t < 256)      rk = *(const half8v*)(K + (size_t)(b * 1024 + (K0) + sd) * 1024 + h * 64 + sc * 8); \
    else if (t < 512) rv = *(const half8v*)(VT + (size_t)(h * 64 + vd) * 8192 + b * 1024 + (K0) + vc * 8);

  ISSUE_LOADS(0)

  for (int kt = 0; kt < 32; ++kt) {
    const int c = kt & 1;
    if (t < 256)      *(half8v*)&sK[c][(sc * 32 + sd) * 8] = rk;
    else if (t < 512) *(half8v*)&sV[c][vd * 40 + vc * 8] = rv;
    if (kt + 1 < 32) { ISSUE_LOADS((kt + 1) * 32) }
    __syncthreads();   // barB: buf[c] ready

    // ---- S = Q.K^T
    f32x4 s[2][2];
    #pragma unroll
    for (int i = 0; i < 2; ++i)
      #pragma unroll
      for (int j = 0; j < 2; ++j) { f32x4 z = {0.f, 0.f, 0.f, 0.f}; s[i][j] = z; }
    __builtin_amdgcn_s_setprio(1);
    #pragma unroll
    for (int dh = 0; dh < 2; ++dh) {
      half8v kb[2];
      #pragma unroll
      for (int fi = 0; fi < 2; ++fi)
        kb[fi] = *(const half8v*)&sK[c][((dh * 4 + lq) * 32 + fi * 16 + lm) * 8];
      #pragma unroll
      for (int mi = 0; mi < 2; ++mi)
        #pragma unroll
        for (int fi = 0; fi < 2; ++fi)
          s[mi][fi] = __builtin_amdgcn_mfma_f32_16x16x32_f16(qf[mi][dh], kb[fi], s[mi][fi], 0, 0, 0);
    }
    __builtin_amdgcn_s_setprio(0);

    // ---- exp + per-wave column partials (k = fi*16+lm)
    float zp[2] = {0.f, 0.f};
    #pragma unroll
    for (int mi = 0; mi < 2; ++mi)
      #pragma unroll
      for (int fi = 0; fi < 2; ++fi)
        #pragma unroll
        for (int j = 0; j < 4; ++j) {
          float p = __expf(s[mi][fi][j] * 0.03125f);   // scores tiny: no max-sub
          s[mi][fi][j] = p;
          zp[fi] += p;
        }
    #pragma unroll
    for (int fi = 0; fi < 2; ++fi) {
      zp[fi] += __shfl_xor(zp[fi], 16);
      zp[fi] += __shfl_xor(zp[fi], 32);
    }
    if (lane < 16) { sZ[w][lm] = zp[0]; sZ[w][16 + lm] = zp[1]; }
    __syncthreads();   // barC: sZ complete

    // ---- invZ: lanes<32 own one k column each, shfl-distribute
    float iz = 0.f;
    if (lane < 32) {
      float z = 0.f;
      #pragma unroll
      for (int wv = 0; wv < 16; ++wv) z += sZ[wv][lane];
      iz = 1.0f / z;
    }
    const float iz0 = __shfl(iz, lm);
    const float iz1 = __shfl(iz, 16 + lm);

    // ---- P*invZ -> per-wave LDS (fp16); intra-wave only, no barrier
    #pragma unroll
    for (int mi = 0; mi < 2; ++mi)
      #pragma unroll
      for (int j = 0; j < 4; ++j) {
        const int q = mi * 16 + lq * 4 + j;
        sPw[q * 40 + lm]      = (_Float16)(s[mi][0][j] * iz0);
        sPw[q * 40 + 16 + lm] = (_Float16)(s[mi][1][j] * iz1);
      }

    // ---- PV: O += P . V
    half8v pa[2], vb[4];
    #pragma unroll
    for (int mi = 0; mi < 2; ++mi)
      pa[mi] = *(const half8v*)&sPw[(mi * 16 + lm) * 40 + lq * 8];
    #pragma unroll
    for (int ni = 0; ni < 4; ++ni)
      vb[ni] = *(const half8v*)&sV[c][(ni * 16 + lm) * 40 + lq * 8];
    __builtin_amdgcn_s_setprio(1);
    #pragma unroll
    for (int mi = 0; mi < 2; ++mi)
      #pragma unroll
      for (int ni = 0; ni < 4; ++ni)
        o[mi][ni] = __builtin_amdgcn_mfma_f32_16x16x32_f16(pa[mi], vb[ni], o[mi][ni], 0, 0, 0);
    __builtin_amdgcn_s_setprio(0);
  }
  #undef ISSUE_LOADS

  // ---- epilogue: Opart[ks][hb][q][d]
  float* dst = Opart + (size_t)(ks * 128 + hb) * 512 * 64;
  #pragma unroll
  for (int mi = 0; mi < 2; ++mi)
    #pragma unroll
    for (int ni = 0; ni < 4; ++ni)
      #pragma unroll
      for (int j = 0; j < 4; ++j) {
        const int q = qw + mi * 16 + lq * 4 + j;
        const int d = ni * 16 + lm;
        dst[(size_t)q * 64 + d] = o[mi][ni][j];
      }
}

// ============ LayerNorm ============
// MODE 0: v = Qp(fp16) + Op[0] + Op[1] (merge-heads+residual); out fp16
// MODE 1: v = fin[row]; out fp32
template<int MODE>
__global__ __launch_bounds__(256)
void ln_kernel(const float* __restrict__ fin, const _Float16* __restrict__ Qp,
               const float* __restrict__ g, const float* __restrict__ beta,
               _Float16* __restrict__ oh, float* __restrict__ of) {
  const int row = blockIdx.x;          // b*512 + n
  const int t = threadIdx.x;
  const int c = t * 4;
  float4 v;
  if (MODE == 0) {
    const int b  = row >> 9;
    const int n  = row & 511;
    const int hh = c >> 6;
    const int d  = c & 63;
    const int hb = hh * 8 + b;
    half4v qv = *(const half4v*)(Qp + (size_t)row * 1024 + c);
    float4 p0 = *(const float4*)&fin[((size_t)hb         * 512 + n) * 64 + d];
    float4 p1 = *(const float4*)&fin[((size_t)(128 + hb) * 512 + n) * 64 + d];
    v = make_float4((float)qv[0] + p0.x + p1.x, (float)qv[1] + p0.y + p1.y,
                    (float)qv[2] + p0.z + p1.z, (float)qv[3] + p0.w + p1.w);
  } else {
    v = *(const float4*)&fin[(size_t)row * 1024 + c];
  }
  float s  = v.x + v.y + v.z + v.w;
  float s2 = v.x * v.x + v.y * v.y + v.z * v.z + v.w * v.w;
  #pragma unroll
  for (int m = 1; m < 64; m <<= 1) { s += __shfl_xor(s, m); s2 += __shfl_xor(s2, m); }
  __shared__ float aS[4], aS2[4];
  const int wid = t >> 6;
  if ((t & 63) == 0) { aS[wid] = s; aS2[wid] = s2; }
  __syncthreads();
  s  = aS[0] + aS[1] + aS[2] + aS[3];
  s2 = aS2[0] + aS2[1] + aS2[2] + aS2[3];
  const float mean = s * (1.f / 1024.f);
  const float var  = s2 * (1.f / 1024.f) - mean * mean;
  const float rstd = rsqrtf(var + 1e-5f);
  float4 gg = *(const float4*)&g[c];
  float4 bb = *(const float4*)&beta[c];
  float4 ov = make_float4((v.x - mean) * rstd * gg.x + bb.x,
                          (v.y - mean) * rstd * gg.y + bb.y,
                          (v.z - mean) * rstd * gg.z + bb.z,
                          (v.w - mean) * rstd * gg.w + bb.w);
  const size_t oi = (size_t)row * 1024 + c;
  if (MODE == 0) {
    half4v hv;
    hv[0] = (_Float16)ov.x; hv[1] = (_Float16)ov.y;
    hv[2] = (_Float16)ov.z; hv[3] = (_Float16)ov.w;
    *(half4v*)(oh + oi) = hv;
  } else {
    *(float4*)(of + oi) = ov;
  }
}

extern "C" void kernel_launch(void* const* d_in, const int* in_sizes, int n_in,
                              void* d_out, int out_size, void* d_ws, size_t ws_size,
                              hipStream_t stream) {
  (void)in_sizes; (void)n_in; (void)out_size; (void)ws_size;
  const float* Q   = (const float*)d_in[0];
  const float* K1  = (const float*)d_in[1];
  const float* K2  = (const float*)d_in[2];
  const float* Wq  = (const float*)d_in[3];
  const float* bq  = (const float*)d_in[4];
  const float* Wk1 = (const float*)d_in[5];
  const float* bk1 = (const float*)d_in[6];
  const float* Wk2 = (const float*)d_in[7];
  const float* bk2 = (const float*)d_in[8];
  const float* Wv1 = (const float*)d_in[9];
  const float* bv1 = (const float*)d_in[10];
  const float* Wv2 = (const float*)d_in[11];
  const float* bv2 = (const float*)d_in[12];
  const float* Wo  = (const float*)d_in[13];
  const float* bo  = (const float*)d_in[14];
  const float* g0  = (const float*)d_in[15];
  const float* be0 = (const float*)d_in[16];
  const float* g1  = (const float*)d_in[17];
  const float* be1 = (const float*)d_in[18];

  // ---- workspace layout (MB offsets; total 169 MB) ----
  // 0 Qc(8) | 8 K1c(16) | 24 K2c(16) | 40 Wt0..5 (2 each, ends 52) |
  // 52 Wk1c(2) | 54 Wk2c(2) | 56 Wc1(4: rows0-1023=Wk1t, rows1024-2047=composed) |
  // 60 Wc2(4) | 64 misc: bc1(8KB), bc2(8KB @ +8KB), zb(4KB @ +16KB) |
  // 65 Qp(8) | 73 K1p(16) | 89 K2p(16) | 105 VT1(16) | 121 VT2(16) | 137 Op fp32(32)
  // overlays: x0 = [0,8) (Qc dead), tb fp32 = [8,24) (K1c dead)
  char* WS = (char*)d_ws;
  const size_t MB = 1024 * 1024;
  auto S = [&](size_t off) { return (_Float16*)(WS + off); };
  _Float16 *Qc = S(0), *K1c = S(8 * MB), *K2c = S(24 * MB);
  _Float16 *Wt[6];
  for (int i = 0; i < 6; ++i) Wt[i] = S(40 * MB + i * 2 * MB);
  _Float16 *Wk1c = S(52 * MB), *Wk2c = S(54 * MB);
  _Float16 *Wc1 = S(56 * MB), *Wc2 = S(60 * MB);
  float *bc1 = (float*)(WS + 64 * MB);
  float *bc2 = (float*)(WS + 64 * MB + 8 * 1024);
  float *zb  = (float*)(WS + 64 * MB + 16 * 1024);
  _Float16 *Qp  = S(65 * MB);
  _Float16 *K1p = S(73 * MB), *K2p = S(89 * MB);
  _Float16 *VT1 = S(105 * MB), *VT2 = S(121 * MB);
  float* Op = (float*)(WS + 137 * MB);
  _Float16 *x0 = S(0);                    // overlays Qc
  float* tb = (float*)(WS + 8 * MB);      // overlays K1c

  WPArgs wa;
  const float* wsrc[6] = {Wq, Wk1, Wk2, Wv1, Wv2, Wo};
  _Float16* wdst[6] = {Wt[0], Wc1 /*rows 0-1023*/, Wc2 /*rows 0-1023*/, Wt[3], Wt[4], Wt[5]};
  for (int i = 0; i < 6; ++i) { wa.w[i].src = wsrc[i]; wa.w[i].dst = wdst[i]; }

  // ---- prep ----
  wprep_kernel<<<dim3(32, 32, 6), 256, 0, stream>>>(wa);
  aconv_kernel<<<dim3(4096), 256, 0, stream>>>(Q,   Qc,   1048576);
  aconv_kernel<<<dim3(8192), 256, 0, stream>>>(K1,  K1c,  2097152);
  aconv_kernel<<<dim3(8192), 256, 0, stream>>>(K2,  K2c,  2097152);
  aconv_kernel<<<dim3(1024), 256, 0, stream>>>(Wk1, Wk1c, 262144);
  aconv_kernel<<<dim3(1024), 256, 0, stream>>>(Wk2, Wk2c, 262144);
  hipMemsetAsync(zb, 0, 4096, stream);
  hipMemcpyAsync(bc1, bk1, 4096, hipMemcpyDeviceToDevice, stream);
  hipMemcpyAsync(bc2, bk2, 4096, hipMemcpyDeviceToDevice, stream);
  bias_compose<<<dim3(4), 256, 0, stream>>>(bk1, bv1, Wt[3], bc1 + 1024);
  bias_compose<<<dim3(4), 256, 0, stream>>>(bk2, bv2, Wt[4], bc2 + 1024);

  // ---- composed weights: Wc[1024+n][k] = (Wk@Wv)^T  (MODE 2, ostride 1024) ----
  gemm_fp16<2><<<dim3(64), 256, 0, stream>>>(Wk1c, Wt[3], zb, nullptr,
                                             nullptr, nullptr, Wc1 + (size_t)1024 * 1024, 8, 8, 1024);
  gemm_fp16<2><<<dim3(64), 256, 0, stream>>>(Wk2c, Wt[4], zb, nullptr,
                                             nullptr, nullptr, Wc2 + (size_t)1024 * 1024, 8, 8, 1024);

  // ---- projections ----
  gemm_fp16<0><<<dim3(256),  256, 0, stream>>>(Qc,  Wt[0], bq, nullptr, Qp, nullptr, nullptr, 32, 8, 0);
  // combined: K-proj (cols 0-1023 -> K1p) + V-proj (cols 1024-2047 -> VT1 transposed)
  gemm_fp16<3><<<dim3(1024), 256, 0, stream>>>(K1c, Wc1, bc1, nullptr, K1p, nullptr, VT1, 64, 16, 8192);
  gemm_fp16<3><<<dim3(1024), 256, 0, stream>>>(K2c, Wc2, bc2, nullptr, K2p, nullptr, VT2, 64, 16, 8192);

  attn_mfma<<<dim3(128, 2), dim3(1024), 0, stream>>>(Qp, K1p, K2p, VT1, VT2, Op);

  ln_kernel<0><<<dim3(4096), 256, 0, stream>>>(Op, Qp, g0, be0, x0, nullptr);
  gemm_fp16<1><<<dim3(256), 256, 0, stream>>>(x0, Wt[5], bo, x0, nullptr, tb, nullptr, 32, 8, 0);
  ln_kernel<1><<<dim3(4096), 256, 0, stream>>>(tb, nullptr, g1, be1, nullptr, (float*)d_out);
}